// Round 1
// baseline (346.261 us; speedup 1.0000x reference)
//
#include <hip/hip_runtime.h>

#define BS    32
#define LSEQ  512
#define DIM   512
#define NCH   32
#define NDICT 97

// 2*log2(e): tanh(x) = 1 - 2/(1 + 2^(x * 2*log2(e)))
#define TANH_SCALE 2.8853900817779268f

__device__ __forceinline__ float tanh_from_scaled(float xs) {
    float e2 = __builtin_amdgcn_exp2f(xs);
    float r  = __builtin_amdgcn_rcpf(1.0f + e2);
    return fmaf(-2.0f, r, 1.0f);
}

// ---------------- kernel 1: w_o = (emb @ Wo_w + Wo_b) * TANH_SCALE   (32 x 512)
__global__ __launch_bounds__(256) void k_wo(
    const float* __restrict__ emb, const float* __restrict__ Wo_w,
    const float* __restrict__ Wo_b, float* __restrict__ w_o)
{
    const int n = blockIdx.x;
    const int t = threadIdx.x;
    __shared__ float embS[DIM];
    embS[t]       = emb[n * DIM + t];
    embS[t + 256] = emb[n * DIM + t + 256];
    __syncthreads();
    float acc0 = Wo_b[t], acc1 = Wo_b[t + 256];
    for (int k = 0; k < DIM; ++k) {
        float ek = embS[k];
        acc0 = fmaf(ek, Wo_w[k * DIM + t], acc0);
        acc1 = fmaf(ek, Wo_w[k * DIM + t + 256], acc1);
    }
    w_o[n * DIM + t]       = acc0 * TANH_SCALE;
    w_o[n * DIM + t + 256] = acc1 * TANH_SCALE;
}

// ---------------- kernel 2: w_v = inp @ Wv_w + Wv_b   (M=16384, K=512, N=512) fp32
// BM=128, BN=64, BK=16, 256 threads, 8x4 micro-tile
__global__ __launch_bounds__(256) void k_wv(
    const float* __restrict__ A, const float* __restrict__ B,
    const float* __restrict__ bias, float* __restrict__ C)
{
    const int K = DIM, N = DIM;
    __shared__ float As[16][132];   // As[k][m], padded
    __shared__ float Bs[16][68];    // Bs[k][n], padded
    const int bm = blockIdx.y * 128;
    const int bn = blockIdx.x * 64;
    const int t  = threadIdx.x;

    const int ar4 = t >> 2;          // 0..63 (row group; also +64)
    const int ac4 = (t & 3) * 4;     // 0,4,8,12
    const int br  = t >> 4;          // 0..15
    const int bc  = (t & 15) * 4;    // 0..60
    const int tm  = (t >> 4) * 8;    // 0..120
    const int tn  = (t & 15) * 4;    // 0..60

    float acc[8][4];
    #pragma unroll
    for (int i = 0; i < 8; ++i)
        #pragma unroll
        for (int j = 0; j < 4; ++j) acc[i][j] = 0.0f;

    const float* ApA = A + (bm + ar4) * K + ac4;
    const float* ApB = A + (bm + ar4 + 64) * K + ac4;
    const float* Bp  = B + br * N + bn + bc;

    for (int k0 = 0; k0 < K; k0 += 16) {
        float4 aA = *(const float4*)(ApA + k0);
        float4 aB = *(const float4*)(ApB + k0);
        float4 bv = *(const float4*)(Bp + k0 * N);
        As[ac4 + 0][ar4] = aA.x; As[ac4 + 1][ar4] = aA.y;
        As[ac4 + 2][ar4] = aA.z; As[ac4 + 3][ar4] = aA.w;
        As[ac4 + 0][ar4 + 64] = aB.x; As[ac4 + 1][ar4 + 64] = aB.y;
        As[ac4 + 2][ar4 + 64] = aB.z; As[ac4 + 3][ar4 + 64] = aB.w;
        *(float4*)&Bs[br][bc] = bv;
        __syncthreads();
        #pragma unroll
        for (int kk = 0; kk < 16; ++kk) {
            float a[8], b[4];
            *(float4*)&a[0] = *(const float4*)&As[kk][tm];
            *(float4*)&a[4] = *(const float4*)&As[kk][tm + 4];
            *(float4*)&b[0] = *(const float4*)&Bs[kk][tn];
            #pragma unroll
            for (int i = 0; i < 8; ++i)
                #pragma unroll
                for (int j = 0; j < 4; ++j)
                    acc[i][j] = fmaf(a[i], b[j], acc[i][j]);
        }
        __syncthreads();
    }

    #pragma unroll
    for (int i = 0; i < 8; ++i) {
        const int m = bm + tm + i;
        float4 o;
        o.x = acc[i][0] + bias[bn + tn + 0];
        o.y = acc[i][1] + bias[bn + tn + 1];
        o.z = acc[i][2] + bias[bn + tn + 2];
        o.w = acc[i][3] + bias[bn + tn + 3];
        *(float4*)&C[m * N + bn + tn] = o;
    }
}

// ---------------- kernel 3: e[b,n,l] = sum_d tanh(w_o[n,d] + w_v[b,l,d]) * We[d]
// grid (L/4, BS); 4 waves/block, one l per wave; d split over 64 lanes (8 each).
// w_o rows are pre-scaled by TANH_SCALE; stored in LDS with XOR granule swizzle.
__global__ __launch_bounds__(256) void k_e(
    const float* __restrict__ w_v, const float* __restrict__ w_o,
    const float* __restrict__ We_w, float* __restrict__ e)
{
    __shared__ float4 woS[NCH * 128];  // 64 KB
    const int b  = blockIdx.y;
    const int l0 = blockIdx.x * 4;
    const int t  = threadIdx.x;

    const float4* wog = (const float4*)w_o;
    for (int i = t; i < NCH * 128; i += 256) {
        int g = i & 127;
        int p = g ^ ((g >> 3) & 1);
        woS[(i & ~127) | p] = wog[i];
    }
    __syncthreads();

    const int wave = t >> 6, lane = t & 63;
    const int l = l0 + wave;

    const float4* wvp = (const float4*)(w_v + (b * LSEQ + l) * DIM);
    float4 wv0 = wvp[2 * lane], wv1 = wvp[2 * lane + 1];
    wv0.x *= TANH_SCALE; wv0.y *= TANH_SCALE; wv0.z *= TANH_SCALE; wv0.w *= TANH_SCALE;
    wv1.x *= TANH_SCALE; wv1.y *= TANH_SCALE; wv1.z *= TANH_SCALE; wv1.w *= TANH_SCALE;

    const float4* wep = (const float4*)We_w;
    const float4 we0 = wep[2 * lane], we1 = wep[2 * lane + 1];

    const int g0 = 2 * lane, g1 = 2 * lane + 1;
    const int p0 = g0 ^ ((g0 >> 3) & 1);
    const int p1 = g1 ^ ((g1 >> 3) & 1);

    float* eout = e + b * NCH * LSEQ + l;
    #pragma unroll 4
    for (int n = 0; n < NCH; ++n) {
        const float4 wo0 = woS[(n << 7) + p0];
        const float4 wo1 = woS[(n << 7) + p1];
        float s;
        s = tanh_from_scaled(wo0.x + wv0.x) * we0.x;
        s = fmaf(tanh_from_scaled(wo0.y + wv0.y), we0.y, s);
        s = fmaf(tanh_from_scaled(wo0.z + wv0.z), we0.z, s);
        s = fmaf(tanh_from_scaled(wo0.w + wv0.w), we0.w, s);
        s = fmaf(tanh_from_scaled(wo1.x + wv1.x), we1.x, s);
        s = fmaf(tanh_from_scaled(wo1.y + wv1.y), we1.y, s);
        s = fmaf(tanh_from_scaled(wo1.z + wv1.z), we1.z, s);
        s = fmaf(tanh_from_scaled(wo1.w + wv1.w), we1.w, s);
        #pragma unroll
        for (int off = 32; off > 0; off >>= 1) s += __shfl_xor(s, off, 64);
        if (lane == 0) eout[n * LSEQ] = s;
    }
}

// ---------------- kernel 4: softmax over l (We_b dropped: shift-invariant),
// vf = alpha @ inp, logits = vf @ Wc + b. Block per (b, 4 chars).
__global__ __launch_bounds__(256) void k_att(
    const float* __restrict__ e, const float* __restrict__ inp,
    const float* __restrict__ Wc_w, const float* __restrict__ Wc_b,
    float* __restrict__ out_vf, float* __restrict__ out_logits)
{
    __shared__ float alphaS[4][LSEQ];
    __shared__ float vfS[4][DIM];
    const int b  = blockIdx.x >> 3;
    const int n0 = (blockIdx.x & 7) * 4;
    const int t  = threadIdx.x;
    const int wave = t >> 6, lane = t & 63;

    {   // softmax of row (b, n0+wave), one wave per row
        const float4* erow = (const float4*)(e + (b * NCH + n0 + wave) * LSEQ);
        float4 v0 = erow[2 * lane], v1 = erow[2 * lane + 1];
        float m = fmaxf(fmaxf(fmaxf(v0.x, v0.y), fmaxf(v0.z, v0.w)),
                        fmaxf(fmaxf(v1.x, v1.y), fmaxf(v1.z, v1.w)));
        #pragma unroll
        for (int off = 32; off > 0; off >>= 1) m = fmaxf(m, __shfl_xor(m, off, 64));
        float p0 = __expf(v0.x - m), p1 = __expf(v0.y - m);
        float p2 = __expf(v0.z - m), p3 = __expf(v0.w - m);
        float p4 = __expf(v1.x - m), p5 = __expf(v1.y - m);
        float p6 = __expf(v1.z - m), p7 = __expf(v1.w - m);
        float s = ((p0 + p1) + (p2 + p3)) + ((p4 + p5) + (p6 + p7));
        #pragma unroll
        for (int off = 32; off > 0; off >>= 1) s += __shfl_xor(s, off, 64);
        const float inv = 1.0f / s;
        float4 a0 = make_float4(p0 * inv, p1 * inv, p2 * inv, p3 * inv);
        float4 a1 = make_float4(p4 * inv, p5 * inv, p6 * inv, p7 * inv);
        ((float4*)&alphaS[wave][0])[2 * lane]     = a0;
        ((float4*)&alphaS[wave][0])[2 * lane + 1] = a1;
    }
    __syncthreads();

    // vf accumulation: each thread owns d = t and t+256, all 4 chars
    float acc[4][2];
    #pragma unroll
    for (int r = 0; r < 4; ++r) { acc[r][0] = 0.0f; acc[r][1] = 0.0f; }
    const float* ib = inp + b * LSEQ * DIM + t;
    #pragma unroll 4
    for (int l = 0; l < LSEQ; ++l) {
        float x0 = ib[l * DIM];
        float x1 = ib[l * DIM + 256];
        #pragma unroll
        for (int r = 0; r < 4; ++r) {
            float al = alphaS[r][l];
            acc[r][0] = fmaf(al, x0, acc[r][0]);
            acc[r][1] = fmaf(al, x1, acc[r][1]);
        }
    }
    #pragma unroll
    for (int r = 0; r < 4; ++r) {
        out_vf[(b * NCH + n0 + r) * DIM + t]       = acc[r][0];
        out_vf[(b * NCH + n0 + r) * DIM + t + 256] = acc[r][1];
        vfS[r][t]       = acc[r][0];
        vfS[r][t + 256] = acc[r][1];
    }
    __syncthreads();

    // logits: 4*97 = 388 outputs
    for (int idx = t; idx < 4 * NDICT; idx += 256) {
        const int r = idx / NDICT, j = idx - r * NDICT;
        float a = Wc_b[j];
        for (int d = 0; d < DIM; ++d)
            a = fmaf(vfS[r][d], Wc_w[d * NDICT + j], a);
        out_logits[(b * NCH + n0 + r) * NDICT + j] = a;
    }
}

extern "C" void kernel_launch(void* const* d_in, const int* in_sizes, int n_in,
                              void* d_out, int out_size, void* d_ws, size_t ws_size,
                              hipStream_t stream)
{
    const float* inp  = (const float*)d_in[0];
    const float* emb  = (const float*)d_in[1];
    const float* Wo_w = (const float*)d_in[2];
    const float* Wo_b = (const float*)d_in[3];
    const float* Wv_w = (const float*)d_in[4];
    const float* Wv_b = (const float*)d_in[5];
    const float* We_w = (const float*)d_in[6];
    // d_in[7] = We_b: unused — softmax over L is shift-invariant and e is not an output
    const float* Wc_w = (const float*)d_in[8];
    const float* Wc_b = (const float*)d_in[9];

    float* w_o = (float*)d_ws;                                            // 64 KB
    float* w_v = (float*)((char*)d_ws + (64 << 10));                      // 33.5 MB
    float* ev  = (float*)((char*)d_ws + (64 << 10) + BS * LSEQ * DIM * 4);// 2 MB
    float* out_vf = (float*)d_out;
    float* out_lg = out_vf + BS * NCH * DIM;

    k_wo<<<dim3(NCH), dim3(256), 0, stream>>>(emb, Wo_w, Wo_b, w_o);
    k_wv<<<dim3(DIM / 64, (BS * LSEQ) / 128), dim3(256), 0, stream>>>(inp, Wv_w, Wv_b, w_v);
    k_e<<<dim3(LSEQ / 4, BS), dim3(256), 0, stream>>>(w_v, w_o, We_w, ev);
    k_att<<<dim3(BS * 8), dim3(256), 0, stream>>>(ev, inp, Wc_w, Wc_b, out_vf, out_lg);
}

// Round 2
// 263.125 us; speedup vs baseline: 1.3160x; 1.3160x over previous
//
#include <hip/hip_runtime.h>

#define BS    32
#define LSEQ  512
#define DIM   512
#define NCH   32
#define NDICT 97
#define CHB   16   // chars per k_e block

// 2*log2(e): tanh(x) = 1 - 2*sigmoid(-2x); sigmoid(-2x) = 1/(1+2^(x*2*log2e))
#define TANH_SCALE 2.8853900817779268f

__device__ __forceinline__ float sig_from_scaled(float xs) {
    float e2 = __builtin_amdgcn_exp2f(xs);
    return __builtin_amdgcn_rcpf(1.0f + e2);
}

// ---------------- kernel 1: w_o = (emb @ Wo_w + Wo_b) * TANH_SCALE   (32 x 512)
__global__ __launch_bounds__(256) void k_wo(
    const float* __restrict__ emb, const float* __restrict__ Wo_w,
    const float* __restrict__ Wo_b, float* __restrict__ w_o)
{
    const int n = blockIdx.x;
    const int t = threadIdx.x;
    __shared__ float embS[DIM];
    embS[t]       = emb[n * DIM + t];
    embS[t + 256] = emb[n * DIM + t + 256];
    __syncthreads();
    float acc0 = Wo_b[t], acc1 = Wo_b[t + 256];
    for (int k = 0; k < DIM; ++k) {
        float ek = embS[k];
        acc0 = fmaf(ek, Wo_w[k * DIM + t], acc0);
        acc1 = fmaf(ek, Wo_w[k * DIM + t + 256], acc1);
    }
    w_o[n * DIM + t]       = acc0 * TANH_SCALE;
    w_o[n * DIM + t + 256] = acc1 * TANH_SCALE;
}

// ---------------- kernel 2: w_v = inp @ Wv_w + Wv_b  (M=16384, K=512, N=512) fp32
// 128x128 tile, 256 threads, 8x8 micro-tile (8 contiguous rows x 2 float4 col-chunks)
__global__ __launch_bounds__(256) void k_wv(
    const float* __restrict__ A, const float* __restrict__ B,
    const float* __restrict__ bias, float* __restrict__ C)
{
    const int K = DIM, N = DIM;
    __shared__ float As[16][132];   // As[k][m]
    __shared__ float Bs[16][132];   // Bs[k][n]
    const int bm = blockIdx.y * 128;
    const int bn = blockIdx.x * 128;
    const int t  = threadIdx.x;

    const int am = t >> 2;            // 0..63 (also +64)
    const int ak = (t & 3) * 4;       // 0,4,8,12
    const int bk = t >> 5;            // 0..7 (also +8)
    const int bc = (t & 31) * 4;      // 0..124
    const int tm = (t >> 4) * 8;      // 0..120
    const int tn = (t & 15) * 4;      // 0..60 (cols tn..tn+3 and tn+64..tn+67)

    float acc[8][8];
    #pragma unroll
    for (int i = 0; i < 8; ++i)
        #pragma unroll
        for (int j = 0; j < 8; ++j) acc[i][j] = 0.0f;

    const float* Ap0 = A + (bm + am) * K + ak;
    const float* Ap1 = Ap0 + 64 * K;
    const float* Bp0 = B + bk * N + bn + bc;
    const float* Bp1 = Bp0 + 8 * N;

    for (int k0 = 0; k0 < K; k0 += 16) {
        float4 a0 = *(const float4*)(Ap0 + k0);
        float4 a1 = *(const float4*)(Ap1 + k0);
        float4 b0 = *(const float4*)(Bp0 + k0 * N);
        float4 b1 = *(const float4*)(Bp1 + k0 * N);
        As[ak + 0][am] = a0.x; As[ak + 1][am] = a0.y;
        As[ak + 2][am] = a0.z; As[ak + 3][am] = a0.w;
        As[ak + 0][am + 64] = a1.x; As[ak + 1][am + 64] = a1.y;
        As[ak + 2][am + 64] = a1.z; As[ak + 3][am + 64] = a1.w;
        *(float4*)&Bs[bk][bc]     = b0;
        *(float4*)&Bs[bk + 8][bc] = b1;
        __syncthreads();
        #pragma unroll
        for (int kk = 0; kk < 16; ++kk) {
            float a[8], b[8];
            *(float4*)&a[0] = *(const float4*)&As[kk][tm];
            *(float4*)&a[4] = *(const float4*)&As[kk][tm + 4];
            *(float4*)&b[0] = *(const float4*)&Bs[kk][tn];
            *(float4*)&b[4] = *(const float4*)&Bs[kk][tn + 64];
            #pragma unroll
            for (int i = 0; i < 8; ++i)
                #pragma unroll
                for (int j = 0; j < 8; ++j)
                    acc[i][j] = fmaf(a[i], b[j], acc[i][j]);
        }
        __syncthreads();
    }

    float4 bi0 = *(const float4*)&bias[bn + tn];
    float4 bi1 = *(const float4*)&bias[bn + tn + 64];
    #pragma unroll
    for (int i = 0; i < 8; ++i) {
        const int m = bm + tm + i;
        float4 o0, o1;
        o0.x = acc[i][0] + bi0.x; o0.y = acc[i][1] + bi0.y;
        o0.z = acc[i][2] + bi0.z; o0.w = acc[i][3] + bi0.w;
        o1.x = acc[i][4] + bi1.x; o1.y = acc[i][5] + bi1.y;
        o1.z = acc[i][6] + bi1.z; o1.w = acc[i][7] + bi1.w;
        *(float4*)&C[m * N + bn + tn]      = o0;
        *(float4*)&C[m * N + bn + tn + 64] = o1;
    }
}

// ---------------- kernel 3: e[b,n,l] = Wsum - 2 * sum_d we_d * sigmoid(-2(wo+wv))
// block: 256 thr = 16 (l,group) x 16 (d-lane); 16 chars per block.
// lane j owns d = 4*(16k+j)+c, k=0..7 -> contiguous 256B group loads, conflict-free LDS.
__global__ __launch_bounds__(256, 4) void k_e(
    const float* __restrict__ w_v, const float* __restrict__ w_o,
    const float* __restrict__ We_w, float* __restrict__ e)
{
    __shared__ float4 woS[CHB * 128];  // 32 KB, linear
    const int lblk = blockIdx.x;            // 0..31
    const int b    = blockIdx.y;
    const int ch0  = blockIdx.z * CHB;
    const int t    = threadIdx.x;

    // stage w_o rows ch0..ch0+15 (linear, coalesced, conflict-free)
    const float4* wog = ((const float4*)w_o) + ch0 * (DIM / 4);
    #pragma unroll
    for (int i = 0; i < 8; ++i)
        woS[t + 256 * i] = wog[t + 256 * i];

    const int wave = t >> 6, lane = t & 63;
    const int g = lane >> 4, j = lane & 15;
    const int l = lblk * 16 + wave * 4 + g;

    const float4* wvp = (const float4*)(w_v + (b * LSEQ + l) * DIM);
    const float4* wep = (const float4*)We_w;
    float4 wv[8], we[8];
    #pragma unroll
    for (int k = 0; k < 8; ++k) {
        wv[k] = wvp[16 * k + j];
        we[k] = wep[16 * k + j];
    }
    #pragma unroll
    for (int k = 0; k < 8; ++k) {
        wv[k].x *= TANH_SCALE; wv[k].y *= TANH_SCALE;
        wv[k].z *= TANH_SCALE; wv[k].w *= TANH_SCALE;
    }
    // Wsum = sum over ALL d of we (16-lane group reduce)
    float wsum = 0.0f;
    #pragma unroll
    for (int k = 0; k < 8; ++k)
        wsum += (we[k].x + we[k].y) + (we[k].z + we[k].w);
    #pragma unroll
    for (int off = 1; off < 16; off <<= 1) wsum += __shfl_xor(wsum, off, 64);

    __syncthreads();

    float res = 0.0f;
    for (int i = 0; i < CHB; ++i) {
        const float4* wrow = &woS[i * 128];
        float s = 0.0f;
        #pragma unroll
        for (int k = 0; k < 8; ++k) {
            float4 wo4 = wrow[16 * k + j];
            s = fmaf(we[k].x, sig_from_scaled(wo4.x + wv[k].x), s);
            s = fmaf(we[k].y, sig_from_scaled(wo4.y + wv[k].y), s);
            s = fmaf(we[k].z, sig_from_scaled(wo4.z + wv[k].z), s);
            s = fmaf(we[k].w, sig_from_scaled(wo4.w + wv[k].w), s);
        }
        #pragma unroll
        for (int off = 1; off < 16; off <<= 1) s += __shfl_xor(s, off, 64);
        if (j == i) res = s;
    }
    // lane (g,j) holds char ch0+j at its l
    e[(b * NCH + ch0 + j) * LSEQ + l] = fmaf(-2.0f, res, wsum);
}

// ---------------- kernel 4: one block per (b,n): softmax + vf + logits
__global__ __launch_bounds__(256) void k_att(
    const float* __restrict__ e, const float* __restrict__ inp,
    const float* __restrict__ Wc_w, const float* __restrict__ Wc_b,
    float* __restrict__ out_vf, float* __restrict__ out_logits)
{
    __shared__ float alphaS[LSEQ];
    __shared__ float vfS[DIM];
    __shared__ float red[8];
    __shared__ float lgS[2][NDICT];

    // cluster all 32 chars of a batch-row on one XCD (round-robin dispatch assumed)
    const int id = blockIdx.x;              // 0..1023
    const int logical = (id & 7) * 128 + (id >> 3);
    const int b = logical >> 5, n = logical & 31;
    const int t = threadIdx.x;
    const int wave = t >> 6, lane = t & 63;

    const float* erow = e + (b * NCH + n) * LSEQ;
    float v0 = erow[t], v1 = erow[t + 256];
    float m = fmaxf(v0, v1);
    #pragma unroll
    for (int off = 32; off > 0; off >>= 1) m = fmaxf(m, __shfl_xor(m, off, 64));
    if (lane == 0) red[wave] = m;
    __syncthreads();
    m = fmaxf(fmaxf(red[0], red[1]), fmaxf(red[2], red[3]));
    float p0 = __expf(v0 - m), p1 = __expf(v1 - m);
    float s = p0 + p1;
    #pragma unroll
    for (int off = 32; off > 0; off >>= 1) s += __shfl_xor(s, off, 64);
    if (lane == 0) red[4 + wave] = s;
    __syncthreads();
    s = (red[4] + red[5]) + (red[6] + red[7]);
    const float inv = 1.0f / s;
    alphaS[t]       = p0 * inv;
    alphaS[t + 256] = p1 * inv;
    __syncthreads();

    // vf: thread owns d = 2t, 2t+1 (float2)
    float ax = 0.0f, ay = 0.0f;
    const float2* ib2 = ((const float2*)(inp + b * LSEQ * DIM)) + t;
    #pragma unroll 8
    for (int l = 0; l < LSEQ; ++l) {
        float2 x = ib2[l * 256];
        float al = alphaS[l];
        ax = fmaf(al, x.x, ax);
        ay = fmaf(al, x.y, ay);
    }
    const int rowbase = (b * NCH + n) * DIM;
    float2 a2; a2.x = ax; a2.y = ay;
    *(float2*)&out_vf[rowbase + 2 * t] = a2;
    *(float2*)&vfS[2 * t] = a2;
    __syncthreads();

    // logits: 2-way d-split over threads {0..96} and {128..224}
    const int j = t & 127, half = t >> 7;
    if (j < NDICT) {
        const float* wc = Wc_w + half * 256 * NDICT + j;
        const float* vv = &vfS[half * 256];
        float a = 0.0f;
        #pragma unroll 4
        for (int d = 0; d < 256; ++d)
            a = fmaf(vv[d], wc[d * NDICT], a);
        lgS[half][j] = a;
    }
    __syncthreads();
    if (t < NDICT)
        out_logits[(b * NCH + n) * NDICT + t] = Wc_b[t] + lgS[0][t] + lgS[1][t];
}

extern "C" void kernel_launch(void* const* d_in, const int* in_sizes, int n_in,
                              void* d_out, int out_size, void* d_ws, size_t ws_size,
                              hipStream_t stream)
{
    const float* inp  = (const float*)d_in[0];
    const float* emb  = (const float*)d_in[1];
    const float* Wo_w = (const float*)d_in[2];
    const float* Wo_b = (const float*)d_in[3];
    const float* Wv_w = (const float*)d_in[4];
    const float* Wv_b = (const float*)d_in[5];
    const float* We_w = (const float*)d_in[6];
    // d_in[7] = We_b: unused (softmax shift-invariant; e not an output)
    const float* Wc_w = (const float*)d_in[8];
    const float* Wc_b = (const float*)d_in[9];

    float* w_o = (float*)d_ws;                                             // 64 KB
    float* w_v = (float*)((char*)d_ws + (64 << 10));                       // 33.5 MB
    float* ev  = (float*)((char*)d_ws + (64 << 10) + BS * LSEQ * DIM * 4); // 2 MB
    float* out_vf = (float*)d_out;
    float* out_lg = out_vf + BS * NCH * DIM;

    k_wo<<<dim3(NCH), dim3(256), 0, stream>>>(emb, Wo_w, Wo_b, w_o);
    k_wv<<<dim3(DIM / 128, (BS * LSEQ) / 128), dim3(256), 0, stream>>>(inp, Wv_w, Wv_b, w_v);
    k_e<<<dim3(LSEQ / 16, BS, NCH / CHB), dim3(256), 0, stream>>>(w_v, w_o, We_w, ev);
    k_att<<<dim3(BS * NCH), dim3(256), 0, stream>>>(ev, inp, Wc_w, Wc_b, out_vf, out_lg);
}

// Round 3
// 198.001 us; speedup vs baseline: 1.7488x; 1.3289x over previous
//
#include <hip/hip_runtime.h>
#include <hip/hip_bf16.h>

#define BS    32
#define LSEQ  512
#define DIM   512
#define NCH   32
#define NDICT 97
#define CHB   16

// 2*log2(e): tanh(x) = 1 - 2*sigmoid(-2x); sigmoid(-2x) = 1/(1+2^(x*2*log2e))
#define TANH_SCALE 2.8853900817779268f

typedef __attribute__((ext_vector_type(8))) short bf16x8;
typedef __attribute__((ext_vector_type(4))) float f32x4;

#define GLDS16(gsrc, ldst) \
  __builtin_amdgcn_global_load_lds((const __attribute__((address_space(1))) void*)(gsrc), \
                                   (__attribute__((address_space(3))) void*)(ldst), 16, 0, 0)

__device__ __forceinline__ float sig_from_scaled(float xs) {
    float e2 = __builtin_amdgcn_exp2f(xs);
    return __builtin_amdgcn_rcpf(1.0f + e2);
}

__device__ __forceinline__ void split_bf16(float a, ushort& h, ushort& l) {
    __hip_bfloat16 bh = __float2bfloat16(a);
    float fh = __bfloat162float(bh);
    __hip_bfloat16 bl = __float2bfloat16(a - fh);
    h = *(ushort*)&bh; l = *(ushort*)&bl;
}

// ---------------- k_prep_a: inp (fp32) -> Ahi, Alo (bf16 planes, [M][K])
__global__ __launch_bounds__(256) void k_prep_a(
    const float* __restrict__ in, ushort* __restrict__ hi, ushort* __restrict__ lo)
{
    const int i0 = blockIdx.x * 256 + threadIdx.x;
    #pragma unroll
    for (int rep = 0; rep < 2; ++rep) {
        const int i = i0 + rep * 1048576;         // total 2097152 float4
        float4 v = ((const float4*)in)[i];
        ushort4 h, l;
        split_bf16(v.x, h.x, l.x); split_bf16(v.y, h.y, l.y);
        split_bf16(v.z, h.z, l.z); split_bf16(v.w, h.w, l.w);
        ((ushort4*)hi)[i] = h;
        ((ushort4*)lo)[i] = l;
    }
}

// ---------------- k_misc: blocks 0..63: Wv -> B^T hi/lo planes ([N][K] bf16)
//                  blocks 64..95: w_o = (emb @ Wo_w + Wo_b) * TANH_SCALE
__global__ __launch_bounds__(256) void k_misc(
    const float* __restrict__ Wv, ushort* __restrict__ BhiT, ushort* __restrict__ BloT,
    const float* __restrict__ emb, const float* __restrict__ Wo_w,
    const float* __restrict__ Wo_b, float* __restrict__ w_o)
{
    __shared__ float tile[64][65];
    const int bid = blockIdx.x;
    const int t = threadIdx.x;
    if (bid < 64) {
        const int k0 = (bid >> 3) * 64, n0 = (bid & 7) * 64;
        const int tr = t >> 4, tc = (t & 15) * 4;
        #pragma unroll
        for (int rr = 0; rr < 64; rr += 16) {
            float4 v = *(const float4*)&Wv[(k0 + rr + tr) * DIM + n0 + tc];
            tile[rr + tr][tc + 0] = v.x; tile[rr + tr][tc + 1] = v.y;
            tile[rr + tr][tc + 2] = v.z; tile[rr + tr][tc + 3] = v.w;
        }
        __syncthreads();
        #pragma unroll
        for (int rr = 0; rr < 64; rr += 16) {
            const int n = rr + tr;
            ushort4 h, l;
            split_bf16(tile[tc + 0][n], h.x, l.x);
            split_bf16(tile[tc + 1][n], h.y, l.y);
            split_bf16(tile[tc + 2][n], h.z, l.z);
            split_bf16(tile[tc + 3][n], h.w, l.w);
            *(ushort4*)&BhiT[(size_t)(n0 + n) * DIM + k0 + tc] = h;
            *(ushort4*)&BloT[(size_t)(n0 + n) * DIM + k0 + tc] = l;
        }
    } else {
        const int n = bid - 64;
        float* embS = &tile[0][0];
        embS[t]       = emb[n * DIM + t];
        embS[t + 256] = emb[n * DIM + t + 256];
        __syncthreads();
        float acc0 = Wo_b[t], acc1 = Wo_b[t + 256];
        for (int k = 0; k < DIM; ++k) {
            float ek = embS[k];
            acc0 = fmaf(ek, Wo_w[k * DIM + t], acc0);
            acc1 = fmaf(ek, Wo_w[k * DIM + t + 256], acc1);
        }
        w_o[n * DIM + t]       = acc0 * TANH_SCALE;
        w_o[n * DIM + t + 256] = acc1 * TANH_SCALE;
    }
}

// ---------------- k_gemm: w_v = inp @ Wv + b via split-bf16 MFMA (3 passes fused)
// 128x128 tile, BK=64, 4 waves (2x2), each wave 64x64 out (4x4 frags of 16x16x32).
// LDS planes staged by global_load_lds w=16 with XOR granule swizzle (src-side).
__global__ __launch_bounds__(256) void k_gemm(
    const ushort* __restrict__ Ahi, const ushort* __restrict__ Alo,
    const ushort* __restrict__ Bhi, const ushort* __restrict__ Blo,
    const float* __restrict__ bias, float* __restrict__ C)
{
    __shared__ ushort Ah[128 * 64], Al[128 * 64], Bh[128 * 64], Bl[128 * 64]; // 64 KB

    // XCD-chunked mapping: 512 blocks, xcd = bid&7 gets 16 consecutive m-blocks x 4 n-blocks
    const int bid = blockIdx.x;
    const int mb = (bid & 7) * 16 + (bid >> 5);
    const int nb = (bid >> 3) & 3;
    const int bm = mb * 128, bn = nb * 128;

    const int t = threadIdx.x;
    const int wave = t >> 6, lane = t & 63;
    const int wm = wave >> 1, wn = wave & 1;

    // staging constants: lane granule (rl, pl), source granule g = pl ^ rl
    const int rl = lane >> 3;
    const int gsw = (lane & 7) ^ rl;

    f32x4 acc[4][4] = {};

    for (int k0 = 0; k0 < DIM; k0 += 64) {
        #pragma unroll
        for (int c4 = 0; c4 < 4; ++c4) {
            const int c = wave * 4 + c4;
            const size_t ra = (size_t)(bm + c * 8 + rl) * DIM + k0 + gsw * 8;
            const size_t rb = (size_t)(bn + c * 8 + rl) * DIM + k0 + gsw * 8;
            GLDS16(Ahi + ra, &Ah[c * 512]);
            GLDS16(Alo + ra, &Al[c * 512]);
            GLDS16(Bhi + rb, &Bh[c * 512]);
            GLDS16(Blo + rb, &Bl[c * 512]);
        }
        __syncthreads();

        #pragma unroll
        for (int kh = 0; kh < 2; ++kh) {
            const int gc = kh * 4 + (lane >> 4);
            const int p  = (gc ^ (lane & 7)) * 8;
            bf16x8 ah[4], al[4], bh[4], bl[4];
            #pragma unroll
            for (int i = 0; i < 4; ++i) {
                const int ra = (wm * 64 + i * 16 + (lane & 15)) * 64 + p;
                const int rb = (wn * 64 + i * 16 + (lane & 15)) * 64 + p;
                ah[i] = *(const bf16x8*)&Ah[ra];
                al[i] = *(const bf16x8*)&Al[ra];
                bh[i] = *(const bf16x8*)&Bh[rb];
                bl[i] = *(const bf16x8*)&Bl[rb];
            }
            #pragma unroll
            for (int i = 0; i < 4; ++i)
                #pragma unroll
                for (int j = 0; j < 4; ++j) {
                    acc[i][j] = __builtin_amdgcn_mfma_f32_16x16x32_bf16(ah[i], bh[j], acc[i][j], 0, 0, 0);
                    acc[i][j] = __builtin_amdgcn_mfma_f32_16x16x32_bf16(ah[i], bl[j], acc[i][j], 0, 0, 0);
                    acc[i][j] = __builtin_amdgcn_mfma_f32_16x16x32_bf16(al[i], bh[j], acc[i][j], 0, 0, 0);
                }
        }
        __syncthreads();
    }

    #pragma unroll
    for (int i = 0; i < 4; ++i) {
        const int m = bm + wm * 64 + i * 16 + (lane >> 4) * 4;
        #pragma unroll
        for (int j = 0; j < 4; ++j) {
            const int n = bn + wn * 64 + j * 16 + (lane & 15);
            const float bb = bias[n];
            #pragma unroll
            for (int r = 0; r < 4; ++r)
                C[(size_t)(m + r) * DIM + n] = acc[i][j][r] + bb;
        }
    }
}

// ---------------- k_e: e[b,n,l] = Wsum - 2 * sum_d we_d * sigmoid(-2(wo+wv))
__global__ __launch_bounds__(256, 4) void k_e(
    const float* __restrict__ w_v, const float* __restrict__ w_o,
    const float* __restrict__ We_w, float* __restrict__ e)
{
    __shared__ float4 woS[CHB * 128];  // 32 KB
    const int lblk = blockIdx.x;
    const int b    = blockIdx.y;
    const int ch0  = blockIdx.z * CHB;
    const int t    = threadIdx.x;

    const float4* wog = ((const float4*)w_o) + ch0 * (DIM / 4);
    #pragma unroll
    for (int i = 0; i < 8; ++i)
        woS[t + 256 * i] = wog[t + 256 * i];

    const int wave = t >> 6, lane = t & 63;
    const int g = lane >> 4, j = lane & 15;
    const int l = lblk * 16 + wave * 4 + g;

    const float4* wvp = (const float4*)(w_v + (size_t)(b * LSEQ + l) * DIM);
    const float4* wep = (const float4*)We_w;
    float4 wv[8], we[8];
    #pragma unroll
    for (int k = 0; k < 8; ++k) {
        wv[k] = wvp[16 * k + j];
        we[k] = wep[16 * k + j];
    }
    #pragma unroll
    for (int k = 0; k < 8; ++k) {
        wv[k].x *= TANH_SCALE; wv[k].y *= TANH_SCALE;
        wv[k].z *= TANH_SCALE; wv[k].w *= TANH_SCALE;
    }
    float wsum = 0.0f;
    #pragma unroll
    for (int k = 0; k < 8; ++k)
        wsum += (we[k].x + we[k].y) + (we[k].z + we[k].w);
    #pragma unroll
    for (int off = 1; off < 16; off <<= 1) wsum += __shfl_xor(wsum, off, 64);

    __syncthreads();

    float res = 0.0f;
    for (int i = 0; i < CHB; ++i) {
        const float4* wrow = &woS[i * 128];
        float s = 0.0f;
        #pragma unroll
        for (int k = 0; k < 8; ++k) {
            float4 wo4 = wrow[16 * k + j];
            s = fmaf(we[k].x, sig_from_scaled(wo4.x + wv[k].x), s);
            s = fmaf(we[k].y, sig_from_scaled(wo4.y + wv[k].y), s);
            s = fmaf(we[k].z, sig_from_scaled(wo4.z + wv[k].z), s);
            s = fmaf(we[k].w, sig_from_scaled(wo4.w + wv[k].w), s);
        }
        #pragma unroll
        for (int off = 1; off < 16; off <<= 1) s += __shfl_xor(s, off, 64);
        if (j == i) res = s;
    }
    e[(size_t)(b * NCH + ch0 + j) * LSEQ + l] = fmaf(-2.0f, res, wsum);
}

// ---------------- k_att: one block per (b,n): softmax + vf + logits
__global__ __launch_bounds__(256) void k_att(
    const float* __restrict__ e, const float* __restrict__ inp,
    const float* __restrict__ Wc_w, const float* __restrict__ Wc_b,
    float* __restrict__ out_vf, float* __restrict__ out_logits)
{
    __shared__ float alphaS[LSEQ];
    __shared__ float vfS[DIM];
    __shared__ float red[8];
    __shared__ float lgS[2][NDICT];

    const int id = blockIdx.x;
    const int logical = (id & 7) * 128 + (id >> 3);
    const int b = logical >> 5, n = logical & 31;
    const int t = threadIdx.x;
    const int wave = t >> 6, lane = t & 63;

    const float* erow = e + (size_t)(b * NCH + n) * LSEQ;
    float v0 = erow[t], v1 = erow[t + 256];
    float m = fmaxf(v0, v1);
    #pragma unroll
    for (int off = 32; off > 0; off >>= 1) m = fmaxf(m, __shfl_xor(m, off, 64));
    if (lane == 0) red[wave] = m;
    __syncthreads();
    m = fmaxf(fmaxf(red[0], red[1]), fmaxf(red[2], red[3]));
    float p0 = __expf(v0 - m), p1 = __expf(v1 - m);
    float s = p0 + p1;
    #pragma unroll
    for (int off = 32; off > 0; off >>= 1) s += __shfl_xor(s, off, 64);
    if (lane == 0) red[4 + wave] = s;
    __syncthreads();
    s = (red[4] + red[5]) + (red[6] + red[7]);
    const float inv = 1.0f / s;
    alphaS[t]       = p0 * inv;
    alphaS[t + 256] = p1 * inv;
    __syncthreads();

    float ax = 0.0f, ay = 0.0f;
    const float2* ib2 = ((const float2*)(inp + (size_t)b * LSEQ * DIM)) + t;
    #pragma unroll 8
    for (int l = 0; l < LSEQ; ++l) {
        float2 x = ib2[l * 256];
        float al = alphaS[l];
        ax = fmaf(al, x.x, ax);
        ay = fmaf(al, x.y, ay);
    }
    const size_t rowbase = (size_t)(b * NCH + n) * DIM;
    float2 a2; a2.x = ax; a2.y = ay;
    *(float2*)&out_vf[rowbase + 2 * t] = a2;
    *(float2*)&vfS[2 * t] = a2;
    __syncthreads();

    const int j = t & 127, half = t >> 7;
    if (j < NDICT) {
        const float* wc = Wc_w + half * 256 * NDICT + j;
        const float* vv = &vfS[half * 256];
        float a = 0.0f;
        #pragma unroll 4
        for (int d = 0; d < 256; ++d)
            a = fmaf(vv[d], wc[d * NDICT], a);
        lgS[half][j] = a;
    }
    __syncthreads();
    if (t < NDICT)
        out_logits[(size_t)(b * NCH + n) * NDICT + t] = Wc_b[t] + lgS[0][t] + lgS[1][t];
}

extern "C" void kernel_launch(void* const* d_in, const int* in_sizes, int n_in,
                              void* d_out, int out_size, void* d_ws, size_t ws_size,
                              hipStream_t stream)
{
    const float* inp  = (const float*)d_in[0];
    const float* emb  = (const float*)d_in[1];
    const float* Wo_w = (const float*)d_in[2];
    const float* Wo_b = (const float*)d_in[3];
    const float* Wv_w = (const float*)d_in[4];
    const float* Wv_b = (const float*)d_in[5];
    const float* We_w = (const float*)d_in[6];
    // d_in[7] = We_b: unused (softmax shift-invariant; e not an output)
    const float* Wc_w = (const float*)d_in[8];
    const float* Wc_b = (const float*)d_in[9];

    char* p = (char*)d_ws;
    float*  w_o  = (float*)p;   p += (64 << 10);
    float*  ev   = (float*)p;   p += (size_t)BS * NCH * LSEQ * 4;     // 2 MB
    ushort* BhiT = (ushort*)p;  p += (size_t)DIM * DIM * 2;           // 512 KB
    ushort* BloT = (ushort*)p;  p += (size_t)DIM * DIM * 2;
    ushort* Ahi  = (ushort*)p;  p += (size_t)BS * LSEQ * DIM * 2;     // 16.8 MB
    ushort* Alo  = (ushort*)p;  p += (size_t)BS * LSEQ * DIM * 2;
    float*  w_v  = (float*)p;                                          // 33.5 MB

    float* out_vf = (float*)d_out;
    float* out_lg = out_vf + BS * NCH * DIM;

    k_prep_a<<<dim3(4096), dim3(256), 0, stream>>>(inp, Ahi, Alo);
    k_misc<<<dim3(96), dim3(256), 0, stream>>>(Wv_w, BhiT, BloT, emb, Wo_w, Wo_b, w_o);
    k_gemm<<<dim3(512), dim3(256), 0, stream>>>(Ahi, Alo, BhiT, BloT, Wv_b, w_v);
    k_e<<<dim3(LSEQ / 16, BS, NCH / CHB), dim3(256), 0, stream>>>(w_v, w_o, We_w, ev);
    k_att<<<dim3(BS * NCH), dim3(256), 0, stream>>>(ev, inp, Wc_w, Wc_b, out_vf, out_lg);
}

// Round 4
// 174.636 us; speedup vs baseline: 1.9828x; 1.1338x over previous
//
#include <hip/hip_runtime.h>
#include <hip/hip_bf16.h>

#define BS    32
#define LSEQ  512
#define DIM   512
#define NCH   32
#define NDICT 97
#define CHB   16

// 2*log2(e): tanh(x) = 1 - 2*sigmoid(-2x); sigmoid(-2x) = 1/(1+2^(x*2*log2e))
#define TANH_SCALE 2.8853900817779268f

typedef __attribute__((ext_vector_type(8))) short bf16x8;
typedef __attribute__((ext_vector_type(4))) float f32x4;

#define GLDS16(gsrc, ldst) \
  __builtin_amdgcn_global_load_lds((const __attribute__((address_space(1))) void*)(gsrc), \
                                   (__attribute__((address_space(3))) void*)(ldst), 16, 0, 0)

__device__ __forceinline__ float sig_from_scaled(float xs) {
    float e2 = __builtin_amdgcn_exp2f(xs);
    return __builtin_amdgcn_rcpf(1.0f + e2);
}

__device__ __forceinline__ void split_bf16(float a, ushort& h, ushort& l) {
    __hip_bfloat16 bh = __float2bfloat16(a);
    float fh = __bfloat162float(bh);
    __hip_bfloat16 bl = __float2bfloat16(a - fh);
    h = *(ushort*)&bh; l = *(ushort*)&bl;
}

// ---------------- k_prep_a: inp (fp32 [b][l][d]) -> AhiT/AloT (bf16 [b][d][l])
// 64x64 tile transpose via padded LDS.
__global__ __launch_bounds__(256) void k_prep_a(
    const float* __restrict__ in, ushort* __restrict__ hiT, ushort* __restrict__ loT)
{
    __shared__ float tile[64][65];
    const int bid = blockIdx.x;
    const int b  = bid >> 6;
    const int l0 = ((bid >> 3) & 7) * 64;
    const int d0 = (bid & 7) * 64;
    const int t  = threadIdx.x;
    const int tr = t >> 4, tc = (t & 15) * 4;

    #pragma unroll
    for (int rr = 0; rr < 4; ++rr) {
        const int l = l0 + rr * 16 + tr;
        float4 v = *(const float4*)&in[((size_t)(b * LSEQ) + l) * DIM + d0 + tc];
        tile[rr * 16 + tr][tc + 0] = v.x; tile[rr * 16 + tr][tc + 1] = v.y;
        tile[rr * 16 + tr][tc + 2] = v.z; tile[rr * 16 + tr][tc + 3] = v.w;
    }
    __syncthreads();
    #pragma unroll
    for (int rr = 0; rr < 4; ++rr) {
        const int dd = rr * 16 + tr;
        ushort4 h, l4;
        split_bf16(tile[tc + 0][dd], h.x, l4.x);
        split_bf16(tile[tc + 1][dd], h.y, l4.y);
        split_bf16(tile[tc + 2][dd], h.z, l4.z);
        split_bf16(tile[tc + 3][dd], h.w, l4.w);
        const size_t o = ((size_t)(b * DIM) + d0 + dd) * LSEQ + l0 + tc;
        *(ushort4*)&hiT[o] = h;
        *(ushort4*)&loT[o] = l4;
    }
}

// ---------------- k_misc: blocks 0..63: Wv -> B^T hi/lo planes ([N][K] bf16)
//                  blocks 64..95: w_o = (emb @ Wo_w + Wo_b) * TANH_SCALE
__global__ __launch_bounds__(256) void k_misc(
    const float* __restrict__ Wv, ushort* __restrict__ BhiT, ushort* __restrict__ BloT,
    const float* __restrict__ emb, const float* __restrict__ Wo_w,
    const float* __restrict__ Wo_b, float* __restrict__ w_o)
{
    __shared__ float tile[64][65];
    const int bid = blockIdx.x;
    const int t = threadIdx.x;
    if (bid < 64) {
        const int k0 = (bid >> 3) * 64, n0 = (bid & 7) * 64;
        const int tr = t >> 4, tc = (t & 15) * 4;
        #pragma unroll
        for (int rr = 0; rr < 64; rr += 16) {
            float4 v = *(const float4*)&Wv[(k0 + rr + tr) * DIM + n0 + tc];
            tile[rr + tr][tc + 0] = v.x; tile[rr + tr][tc + 1] = v.y;
            tile[rr + tr][tc + 2] = v.z; tile[rr + tr][tc + 3] = v.w;
        }
        __syncthreads();
        #pragma unroll
        for (int rr = 0; rr < 64; rr += 16) {
            const int n = rr + tr;
            ushort4 h, l;
            split_bf16(tile[tc + 0][n], h.x, l.x);
            split_bf16(tile[tc + 1][n], h.y, l.y);
            split_bf16(tile[tc + 2][n], h.z, l.z);
            split_bf16(tile[tc + 3][n], h.w, l.w);
            *(ushort4*)&BhiT[(size_t)(n0 + n) * DIM + k0 + tc] = h;
            *(ushort4*)&BloT[(size_t)(n0 + n) * DIM + k0 + tc] = l;
        }
    } else {
        const int n = bid - 64;
        float* embS = &tile[0][0];
        embS[t]       = emb[n * DIM + t];
        embS[t + 256] = emb[n * DIM + t + 256];
        __syncthreads();
        float acc0 = Wo_b[t], acc1 = Wo_b[t + 256];
        for (int k = 0; k < DIM; ++k) {
            float ek = embS[k];
            acc0 = fmaf(ek, Wo_w[k * DIM + t], acc0);
            acc1 = fmaf(ek, Wo_w[k * DIM + t + 256], acc1);
        }
        w_o[n * DIM + t]       = acc0 * TANH_SCALE;
        w_o[n * DIM + t + 256] = acc1 * TANH_SCALE;
    }
}

// ---------------- k_gemm: w_v = inp @ Wv + b, split-bf16 3-pass MFMA.
// A-frags reg-direct from fp32 inp (split in-reg); B from pre-split planes via LDS.
__global__ __launch_bounds__(256) void k_gemm(
    const float* __restrict__ A,
    const ushort* __restrict__ Bhi, const ushort* __restrict__ Blo,
    const float* __restrict__ bias, float* __restrict__ C)
{
    __shared__ ushort Bh[128 * 64], Bl[128 * 64];   // 16 KB each

    const int bid = blockIdx.x;
    const int mb = (bid & 7) * 16 + (bid >> 5);
    const int nb = (bid >> 3) & 3;
    const int bm = mb * 128, bn = nb * 128;

    const int t = threadIdx.x;
    const int wave = t >> 6, lane = t & 63;
    const int wm = wave >> 1, wn = wave & 1;

    const int rl = lane >> 3;
    const int gsw = (lane & 7) ^ rl;

    const int am = bm + wm * 64 + (lane & 15);
    const int ak = (lane >> 4) * 8;

    f32x4 acc[4][4] = {};

    for (int k0 = 0; k0 < DIM; k0 += 64) {
        // A fragments: direct global loads + in-register split
        bf16x8 ah[4][2], al[4][2];
        #pragma unroll
        for (int i = 0; i < 4; ++i)
            #pragma unroll
            for (int kh = 0; kh < 2; ++kh) {
                const float* ap = A + (size_t)(am + i * 16) * DIM + k0 + kh * 32 + ak;
                float4 v0 = *(const float4*)ap;
                float4 v1 = *(const float4*)(ap + 4);
                float vv[8] = {v0.x, v0.y, v0.z, v0.w, v1.x, v1.y, v1.z, v1.w};
                bf16x8 h, l;
                #pragma unroll
                for (int q = 0; q < 8; ++q) {
                    ushort hq, lq; split_bf16(vv[q], hq, lq);
                    h[q] = (short)hq; l[q] = (short)lq;
                }
                ah[i][kh] = h; al[i][kh] = l;
            }
        // B staging (global_load_lds w=16, pre-swizzled source)
        #pragma unroll
        for (int c4 = 0; c4 < 4; ++c4) {
            const int c = wave * 4 + c4;
            const size_t rb = (size_t)(bn + c * 8 + rl) * DIM + k0 + gsw * 8;
            GLDS16(Bhi + rb, &Bh[c * 512]);
            GLDS16(Blo + rb, &Bl[c * 512]);
        }
        __syncthreads();

        #pragma unroll
        for (int kh = 0; kh < 2; ++kh) {
            const int p = ((kh * 4 + (lane >> 4)) ^ (lane & 7)) * 8;
            bf16x8 bh[4], bl[4];
            #pragma unroll
            for (int j = 0; j < 4; ++j) {
                const int rbr = (wn * 64 + j * 16 + (lane & 15)) * 64 + p;
                bh[j] = *(const bf16x8*)&Bh[rbr];
                bl[j] = *(const bf16x8*)&Bl[rbr];
            }
            #pragma unroll
            for (int i = 0; i < 4; ++i)
                #pragma unroll
                for (int j = 0; j < 4; ++j) {
                    acc[i][j] = __builtin_amdgcn_mfma_f32_16x16x32_bf16(ah[i][kh], bh[j], acc[i][j], 0, 0, 0);
                    acc[i][j] = __builtin_amdgcn_mfma_f32_16x16x32_bf16(ah[i][kh], bl[j], acc[i][j], 0, 0, 0);
                    acc[i][j] = __builtin_amdgcn_mfma_f32_16x16x32_bf16(al[i][kh], bh[j], acc[i][j], 0, 0, 0);
                }
        }
        __syncthreads();
    }

    #pragma unroll
    for (int i = 0; i < 4; ++i) {
        const int m = bm + wm * 64 + i * 16 + (lane >> 4) * 4;
        #pragma unroll
        for (int j = 0; j < 4; ++j) {
            const int n = bn + wn * 64 + j * 16 + (lane & 15);
            const float bb = bias[n];
            #pragma unroll
            for (int r = 0; r < 4; ++r)
                C[(size_t)(m + r) * DIM + n] = acc[i][j][r] + bb;
        }
    }
}

// ---------------- k_e: e[b,n,l] = Wsum - 2 * sum_d we_d * sigmoid(-2(wo+wv))
__global__ __launch_bounds__(256, 4) void k_e(
    const float* __restrict__ w_v, const float* __restrict__ w_o,
    const float* __restrict__ We_w, float* __restrict__ e)
{
    __shared__ float4 woS[CHB * 128];  // 32 KB
    const int lblk = blockIdx.x;
    const int b    = blockIdx.y;
    const int ch0  = blockIdx.z * CHB;
    const int t    = threadIdx.x;

    const float4* wog = ((const float4*)w_o) + ch0 * (DIM / 4);
    #pragma unroll
    for (int i = 0; i < 8; ++i)
        woS[t + 256 * i] = wog[t + 256 * i];

    const int wave = t >> 6, lane = t & 63;
    const int g = lane >> 4, j = lane & 15;
    const int l = lblk * 16 + wave * 4 + g;

    const float4* wvp = (const float4*)(w_v + (size_t)(b * LSEQ + l) * DIM);
    const float4* wep = (const float4*)We_w;
    float4 wv[8], we[8];
    #pragma unroll
    for (int k = 0; k < 8; ++k) {
        wv[k] = wvp[16 * k + j];
        we[k] = wep[16 * k + j];
    }
    #pragma unroll
    for (int k = 0; k < 8; ++k) {
        wv[k].x *= TANH_SCALE; wv[k].y *= TANH_SCALE;
        wv[k].z *= TANH_SCALE; wv[k].w *= TANH_SCALE;
    }
    float wsum = 0.0f;
    #pragma unroll
    for (int k = 0; k < 8; ++k)
        wsum += (we[k].x + we[k].y) + (we[k].z + we[k].w);
    #pragma unroll
    for (int off = 1; off < 16; off <<= 1) wsum += __shfl_xor(wsum, off, 64);

    __syncthreads();

    float res = 0.0f;
    for (int i = 0; i < CHB; ++i) {
        const float4* wrow = &woS[i * 128];
        float s = 0.0f;
        #pragma unroll
        for (int k = 0; k < 8; ++k) {
            float4 wo4 = wrow[16 * k + j];
            s = fmaf(we[k].x, sig_from_scaled(wo4.x + wv[k].x), s);
            s = fmaf(we[k].y, sig_from_scaled(wo4.y + wv[k].y), s);
            s = fmaf(we[k].z, sig_from_scaled(wo4.z + wv[k].z), s);
            s = fmaf(we[k].w, sig_from_scaled(wo4.w + wv[k].w), s);
        }
        #pragma unroll
        for (int off = 1; off < 16; off <<= 1) s += __shfl_xor(s, off, 64);
        if (j == i) res = s;
    }
    e[(size_t)(b * NCH + ch0 + j) * LSEQ + l] = fmaf(-2.0f, res, wsum);
}

// ---------------- k_soft: alpha = softmax(e) over l, split to bf16 hi/lo planes.
// grid 256 blocks x 4 waves; one wave per (b,n) row.
__global__ __launch_bounds__(256) void k_soft(
    const float* __restrict__ e, ushort* __restrict__ aH, ushort* __restrict__ aL)
{
    const int row = blockIdx.x * 4 + (threadIdx.x >> 6);
    const int lane = threadIdx.x & 63;
    const float4* erow = (const float4*)(e + (size_t)row * LSEQ);
    float4 v0 = erow[2 * lane], v1 = erow[2 * lane + 1];
    float m = fmaxf(fmaxf(fmaxf(v0.x, v0.y), fmaxf(v0.z, v0.w)),
                    fmaxf(fmaxf(v1.x, v1.y), fmaxf(v1.z, v1.w)));
    #pragma unroll
    for (int off = 32; off > 0; off >>= 1) m = fmaxf(m, __shfl_xor(m, off, 64));
    float p[8];
    p[0] = __expf(v0.x - m); p[1] = __expf(v0.y - m);
    p[2] = __expf(v0.z - m); p[3] = __expf(v0.w - m);
    p[4] = __expf(v1.x - m); p[5] = __expf(v1.y - m);
    p[6] = __expf(v1.z - m); p[7] = __expf(v1.w - m);
    float s = ((p[0] + p[1]) + (p[2] + p[3])) + ((p[4] + p[5]) + (p[6] + p[7]));
    #pragma unroll
    for (int off = 32; off > 0; off >>= 1) s += __shfl_xor(s, off, 64);
    const float inv = 1.0f / s;
    ushort4 h0, h1, l0, l1;
    split_bf16(p[0] * inv, h0.x, l0.x); split_bf16(p[1] * inv, h0.y, l0.y);
    split_bf16(p[2] * inv, h0.z, l0.z); split_bf16(p[3] * inv, h0.w, l0.w);
    split_bf16(p[4] * inv, h1.x, l1.x); split_bf16(p[5] * inv, h1.y, l1.y);
    split_bf16(p[6] * inv, h1.z, l1.z); split_bf16(p[7] * inv, h1.w, l1.w);
    ushort4* oh = (ushort4*)(aH + (size_t)row * LSEQ);
    ushort4* ol = (ushort4*)(aL + (size_t)row * LSEQ);
    oh[2 * lane] = h0; oh[2 * lane + 1] = h1;
    ol[2 * lane] = l0; ol[2 * lane + 1] = l1;
}

// ---------------- k_vf: vf^T(d x n) = inp^T(d x l) @ alpha^T(l x n) per b, 3-pass MFMA.
// grid (8 d-groups, 32 b); 4 waves split the 64 d-rows; full alpha[b] in LDS (swizzled).
__global__ __launch_bounds__(256) void k_vf(
    const ushort* __restrict__ AhiT, const ushort* __restrict__ AloT,
    const ushort* __restrict__ aH, const ushort* __restrict__ aL,
    float* __restrict__ out_vf)
{
    __shared__ ushort BsH[NCH * LSEQ / 1];  // careful: 32*512 ushort = 32 KB
    __shared__ ushort BsL[NCH * LSEQ / 1];
    const int dg = blockIdx.x, b = blockIdx.y;
    const int t = threadIdx.x;
    const int wave = t >> 6, lane = t & 63;

    // stage alpha hi/lo rows with XOR-granule swizzle (64 granules of 8 bf16 per row)
    const ushort* baseH = aH + (size_t)(b * NCH) * LSEQ;
    const ushort* baseL = aL + (size_t)(b * NCH) * LSEQ;
    #pragma unroll
    for (int q = 0; q < 16; ++q) {
        const int idx = wave * 16 + q;
        const int p = idx & 1, n = idx >> 1;
        const int gsrc = lane ^ (n & 7);
        const ushort* src = (p ? baseL : baseH) + (size_t)n * LSEQ + gsrc * 8;
        ushort* dst = (p ? BsL : BsH) + n * LSEQ;
        GLDS16(src, dst);
    }
    __syncthreads();

    const int d = dg * 64 + wave * 16 + (lane & 15);
    const ushort* arow_h = AhiT + ((size_t)(b * DIM) + d) * LSEQ;
    const ushort* arow_l = AloT + ((size_t)(b * DIM) + d) * LSEQ;
    const int koff = (lane >> 4) * 8;

    f32x4 acc[2] = {};
    #pragma unroll 4
    for (int s = 0; s < 16; ++s) {
        bf16x8 ah = *(const bf16x8*)&arow_h[s * 32 + koff];
        bf16x8 al = *(const bf16x8*)&arow_l[s * 32 + koff];
        const int g = ((s * 4 + (lane >> 4)) ^ (lane & 7)) * 8;
        #pragma unroll
        for (int j = 0; j < 2; ++j) {
            const int n = j * 16 + (lane & 15);
            bf16x8 bh = *(const bf16x8*)&BsH[n * LSEQ + g];
            bf16x8 bl = *(const bf16x8*)&BsL[n * LSEQ + g];
            acc[j] = __builtin_amdgcn_mfma_f32_16x16x32_bf16(ah, bh, acc[j], 0, 0, 0);
            acc[j] = __builtin_amdgcn_mfma_f32_16x16x32_bf16(ah, bl, acc[j], 0, 0, 0);
            acc[j] = __builtin_amdgcn_mfma_f32_16x16x32_bf16(al, bh, acc[j], 0, 0, 0);
        }
    }

    const int dw = dg * 64 + wave * 16 + (lane >> 4) * 4;
    #pragma unroll
    for (int j = 0; j < 2; ++j) {
        const int n = j * 16 + (lane & 15);
        #pragma unroll
        for (int r = 0; r < 4; ++r)
            out_vf[(size_t)(b * NCH + n) * DIM + dw + r] = acc[j][r];
    }
}

// ---------------- k_lg: logits = vf @ Wc + b. Block per (b,n).
__global__ __launch_bounds__(256) void k_lg(
    const float* __restrict__ vf, const float* __restrict__ Wc_w,
    const float* __restrict__ Wc_b, float* __restrict__ out_logits)
{
    __shared__ float vfS[DIM];
    __shared__ float lgS[2][NDICT];
    const int row = blockIdx.x;
    const int t = threadIdx.x;
    const float2 v2 = ((const float2*)(vf + (size_t)row * DIM))[t];
    vfS[2 * t] = v2.x; vfS[2 * t + 1] = v2.y;
    __syncthreads();
    const int j = t & 127, half = t >> 7;
    if (j < NDICT) {
        const float* wc = Wc_w + half * 256 * NDICT + j;
        const float* vv = &vfS[half * 256];
        float a = 0.0f;
        #pragma unroll 4
        for (int d = 0; d < 256; ++d)
            a = fmaf(vv[d], wc[d * NDICT], a);
        lgS[half][j] = a;
    }
    __syncthreads();
    if (t < NDICT)
        out_logits[(size_t)row * NDICT + t] = Wc_b[t] + lgS[0][t] + lgS[1][t];
}

extern "C" void kernel_launch(void* const* d_in, const int* in_sizes, int n_in,
                              void* d_out, int out_size, void* d_ws, size_t ws_size,
                              hipStream_t stream)
{
    const float* inp  = (const float*)d_in[0];
    const float* emb  = (const float*)d_in[1];
    const float* Wo_w = (const float*)d_in[2];
    const float* Wo_b = (const float*)d_in[3];
    const float* Wv_w = (const float*)d_in[4];
    const float* Wv_b = (const float*)d_in[5];
    const float* We_w = (const float*)d_in[6];
    // d_in[7] = We_b: unused (softmax shift-invariant; e not an output)
    const float* Wc_w = (const float*)d_in[8];
    const float* Wc_b = (const float*)d_in[9];

    char* p = (char*)d_ws;
    float*  w_o  = (float*)p;   p += (64 << 10);
    float*  ev   = (float*)p;   p += (size_t)BS * NCH * LSEQ * 4;      // 2 MB
    ushort* BhiT = (ushort*)p;  p += (size_t)DIM * DIM * 2;            // 512 KB
    ushort* BloT = (ushort*)p;  p += (size_t)DIM * DIM * 2;
    ushort* aH   = (ushort*)p;  p += (size_t)BS * NCH * LSEQ * 2;      // 1 MB
    ushort* aL   = (ushort*)p;  p += (size_t)BS * NCH * LSEQ * 2;
    ushort* AhiT = (ushort*)p;  p += (size_t)BS * LSEQ * DIM * 2;      // 16.8 MB
    ushort* AloT = (ushort*)p;  p += (size_t)BS * LSEQ * DIM * 2;
    float*  w_v  = (float*)p;                                           // 33.5 MB

    float* out_vf = (float*)d_out;
    float* out_lg = out_vf + BS * NCH * DIM;

    k_prep_a<<<dim3(2048), dim3(256), 0, stream>>>(inp, AhiT, AloT);
    k_misc<<<dim3(96), dim3(256), 0, stream>>>(Wv_w, BhiT, BloT, emb, Wo_w, Wo_b, w_o);
    k_gemm<<<dim3(512), dim3(256), 0, stream>>>(inp, BhiT, BloT, Wv_b, w_v);
    k_e<<<dim3(LSEQ / 16, BS, NCH / CHB), dim3(256), 0, stream>>>(w_v, w_o, We_w, ev);
    k_soft<<<dim3(256), dim3(256), 0, stream>>>(ev, aH, aL);
    k_vf<<<dim3(8, BS), dim3(256), 0, stream>>>(AhiT, AloT, aH, aL, (float*)d_out);
    k_lg<<<dim3(BS * NCH), dim3(256), 0, stream>>>((const float*)d_out, Wc_w, Wc_b, out_lg);
}

// Round 5
// 170.843 us; speedup vs baseline: 2.0268x; 1.0222x over previous
//
#include <hip/hip_runtime.h>
#include <hip/hip_bf16.h>

#define BS    32
#define LSEQ  512
#define DIM   512
#define NCH   32
#define NDICT 97
#define CHB   16

// 2*log2(e): tanh(x) = 1 - 2*sigmoid(-2x); sigmoid(-2x) = 1/(1+2^(x*2*log2e))
#define TANH_SCALE 2.8853900817779268f

typedef __attribute__((ext_vector_type(8))) short bf16x8;
typedef __attribute__((ext_vector_type(4))) float f32x4;

#define GLDS16(gsrc, ldst) \
  __builtin_amdgcn_global_load_lds((const __attribute__((address_space(1))) void*)(gsrc), \
                                   (__attribute__((address_space(3))) void*)(ldst), 16, 0, 0)

__device__ __forceinline__ float sig_from_scaled(float xs) {
    float e2 = __builtin_amdgcn_exp2f(xs);
    return __builtin_amdgcn_rcpf(1.0f + e2);
}

__device__ __forceinline__ void split_bf16(float a, ushort& h, ushort& l) {
    __hip_bfloat16 bh = __float2bfloat16(a);
    float fh = __bfloat162float(bh);
    __hip_bfloat16 bl = __float2bfloat16(a - fh);
    h = *(ushort*)&bh; l = *(ushort*)&bl;
}

// ---------------- k_misc: blocks 0..63: Wv*TANH_SCALE -> B^T hi/lo planes ([N][K] bf16)
//                  blocks 64..95: w_o = (emb @ Wo_w + Wo_b) * TANH_SCALE
__global__ __launch_bounds__(256) void k_misc(
    const float* __restrict__ Wv, ushort* __restrict__ BhiT, ushort* __restrict__ BloT,
    const float* __restrict__ emb, const float* __restrict__ Wo_w,
    const float* __restrict__ Wo_b, float* __restrict__ w_o)
{
    __shared__ float tile[64][65];
    const int bid = blockIdx.x;
    const int t = threadIdx.x;
    if (bid < 64) {
        const int k0 = (bid >> 3) * 64, n0 = (bid & 7) * 64;
        const int tr = t >> 4, tc = (t & 15) * 4;
        #pragma unroll
        for (int rr = 0; rr < 64; rr += 16) {
            float4 v = *(const float4*)&Wv[(k0 + rr + tr) * DIM + n0 + tc];
            tile[rr + tr][tc + 0] = v.x; tile[rr + tr][tc + 1] = v.y;
            tile[rr + tr][tc + 2] = v.z; tile[rr + tr][tc + 3] = v.w;
        }
        __syncthreads();
        #pragma unroll
        for (int rr = 0; rr < 64; rr += 16) {
            const int n = rr + tr;
            ushort4 h, l;
            split_bf16(tile[tc + 0][n] * TANH_SCALE, h.x, l.x);
            split_bf16(tile[tc + 1][n] * TANH_SCALE, h.y, l.y);
            split_bf16(tile[tc + 2][n] * TANH_SCALE, h.z, l.z);
            split_bf16(tile[tc + 3][n] * TANH_SCALE, h.w, l.w);
            *(ushort4*)&BhiT[(size_t)(n0 + n) * DIM + k0 + tc] = h;
            *(ushort4*)&BloT[(size_t)(n0 + n) * DIM + k0 + tc] = l;
        }
    } else {
        const int n = bid - 64;
        float* embS = &tile[0][0];
        embS[t]       = emb[n * DIM + t];
        embS[t + 256] = emb[n * DIM + t + 256];
        __syncthreads();
        float acc0 = Wo_b[t], acc1 = Wo_b[t + 256];
        for (int k = 0; k < DIM; ++k) {
            float ek = embS[k];
            acc0 = fmaf(ek, Wo_w[k * DIM + t], acc0);
            acc1 = fmaf(ek, Wo_w[k * DIM + t + 256], acc1);
        }
        w_o[n * DIM + t]       = acc0 * TANH_SCALE;
        w_o[n * DIM + t + 256] = acc1 * TANH_SCALE;
    }
}

// ---------------- k_gemm: w_v_scaled = TANH_SCALE*(inp @ Wv + b), split-bf16 3-pass MFMA.
// A-frags reg-direct from fp32 inp (split in-reg); B (pre-scaled) planes via LDS.
__global__ __launch_bounds__(256) void k_gemm(
    const float* __restrict__ A,
    const ushort* __restrict__ Bhi, const ushort* __restrict__ Blo,
    const float* __restrict__ bias, float* __restrict__ C)
{
    __shared__ ushort Bh[128 * 64], Bl[128 * 64];   // 16 KB each

    const int bid = blockIdx.x;
    const int mb = (bid & 7) * 16 + (bid >> 5);
    const int nb = (bid >> 3) & 3;
    const int bm = mb * 128, bn = nb * 128;

    const int t = threadIdx.x;
    const int wave = t >> 6, lane = t & 63;
    const int wm = wave >> 1, wn = wave & 1;

    const int rl = lane >> 3;
    const int gsw = (lane & 7) ^ rl;

    const int am = bm + wm * 64 + (lane & 15);
    const int ak = (lane >> 4) * 8;

    f32x4 acc[4][4] = {};

    for (int k0 = 0; k0 < DIM; k0 += 64) {
        // A fragments: direct global loads + in-register split
        bf16x8 ah[4][2], al[4][2];
        #pragma unroll
        for (int i = 0; i < 4; ++i)
            #pragma unroll
            for (int kh = 0; kh < 2; ++kh) {
                const float* ap = A + (size_t)(am + i * 16) * DIM + k0 + kh * 32 + ak;
                float4 v0 = *(const float4*)ap;
                float4 v1 = *(const float4*)(ap + 4);
                float vv[8] = {v0.x, v0.y, v0.z, v0.w, v1.x, v1.y, v1.z, v1.w};
                bf16x8 h, l;
                #pragma unroll
                for (int q = 0; q < 8; ++q) {
                    ushort hq, lq; split_bf16(vv[q], hq, lq);
                    h[q] = (short)hq; l[q] = (short)lq;
                }
                ah[i][kh] = h; al[i][kh] = l;
            }
        // B staging (global_load_lds w=16, pre-swizzled source)
        #pragma unroll
        for (int c4 = 0; c4 < 4; ++c4) {
            const int c = wave * 4 + c4;
            const size_t rb = (size_t)(bn + c * 8 + rl) * DIM + k0 + gsw * 8;
            GLDS16(Bhi + rb, &Bh[c * 512]);
            GLDS16(Blo + rb, &Bl[c * 512]);
        }
        __syncthreads();

        #pragma unroll
        for (int kh = 0; kh < 2; ++kh) {
            const int p = ((kh * 4 + (lane >> 4)) ^ (lane & 7)) * 8;
            bf16x8 bh[4], bl[4];
            #pragma unroll
            for (int j = 0; j < 4; ++j) {
                const int rbr = (wn * 64 + j * 16 + (lane & 15)) * 64 + p;
                bh[j] = *(const bf16x8*)&Bh[rbr];
                bl[j] = *(const bf16x8*)&Bl[rbr];
            }
            #pragma unroll
            for (int i = 0; i < 4; ++i)
                #pragma unroll
                for (int j = 0; j < 4; ++j) {
                    acc[i][j] = __builtin_amdgcn_mfma_f32_16x16x32_bf16(ah[i][kh], bh[j], acc[i][j], 0, 0, 0);
                    acc[i][j] = __builtin_amdgcn_mfma_f32_16x16x32_bf16(ah[i][kh], bl[j], acc[i][j], 0, 0, 0);
                    acc[i][j] = __builtin_amdgcn_mfma_f32_16x16x32_bf16(al[i][kh], bh[j], acc[i][j], 0, 0, 0);
                }
        }
        __syncthreads();
    }

    #pragma unroll
    for (int i = 0; i < 4; ++i) {
        const int m = bm + wm * 64 + i * 16 + (lane >> 4) * 4;
        #pragma unroll
        for (int j = 0; j < 4; ++j) {
            const int n = bn + wn * 64 + j * 16 + (lane & 15);
            const float bb = TANH_SCALE * bias[n];
            #pragma unroll
            for (int r = 0; r < 4; ++r)
                C[(size_t)(m + r) * DIM + n] = acc[i][j][r] + bb;
        }
    }
}

// ---------------- k_e: e[b,n,l] = Wsum - 2 * sum_d we_d * sigmoid-form
// w_v arrives PRE-SCALED by TANH_SCALE (folded into Wv planes + bias).
__global__ __launch_bounds__(256, 4) void k_e(
    const float* __restrict__ w_v, const float* __restrict__ w_o,
    const float* __restrict__ We_w, float* __restrict__ e)
{
    __shared__ float4 woS[CHB * 128];  // 32 KB
    const int lblk = blockIdx.x;
    const int b    = blockIdx.y;
    const int ch0  = blockIdx.z * CHB;
    const int t    = threadIdx.x;

    const float4* wog = ((const float4*)w_o) + ch0 * (DIM / 4);
    #pragma unroll
    for (int i = 0; i < 8; ++i)
        woS[t + 256 * i] = wog[t + 256 * i];

    const int wave = t >> 6, lane = t & 63;
    const int g = lane >> 4, j = lane & 15;
    const int l = lblk * 16 + wave * 4 + g;

    const float4* wvp = (const float4*)(w_v + (size_t)(b * LSEQ + l) * DIM);
    const float4* wep = (const float4*)We_w;
    float4 wv[8], we[8];
    #pragma unroll
    for (int k = 0; k < 8; ++k) {
        wv[k] = wvp[16 * k + j];
        we[k] = wep[16 * k + j];
    }
    float wsum = 0.0f;
    #pragma unroll
    for (int k = 0; k < 8; ++k)
        wsum += (we[k].x + we[k].y) + (we[k].z + we[k].w);
    #pragma unroll
    for (int off = 1; off < 16; off <<= 1) wsum += __shfl_xor(wsum, off, 64);

    __syncthreads();

    float res = 0.0f;
    for (int i = 0; i < CHB; ++i) {
        const float4* wrow = &woS[i * 128];
        float s = 0.0f;
        #pragma unroll
        for (int k = 0; k < 8; ++k) {
            float4 wo4 = wrow[16 * k + j];
            s = fmaf(we[k].x, sig_from_scaled(wo4.x + wv[k].x), s);
            s = fmaf(we[k].y, sig_from_scaled(wo4.y + wv[k].y), s);
            s = fmaf(we[k].z, sig_from_scaled(wo4.z + wv[k].z), s);
            s = fmaf(we[k].w, sig_from_scaled(wo4.w + wv[k].w), s);
        }
        #pragma unroll
        for (int off = 1; off < 16; off <<= 1) s += __shfl_xor(s, off, 64);
        if (j == i) res = s;
    }
    e[(size_t)(b * NCH + ch0 + j) * LSEQ + l] = fmaf(-2.0f, res, wsum);
}

// ---------------- k_soft: alpha = softmax(e) over l, split to bf16 hi/lo planes.
__global__ __launch_bounds__(256) void k_soft(
    const float* __restrict__ e, ushort* __restrict__ aH, ushort* __restrict__ aL)
{
    const int row = blockIdx.x * 4 + (threadIdx.x >> 6);
    const int lane = threadIdx.x & 63;
    const float4* erow = (const float4*)(e + (size_t)row * LSEQ);
    float4 v0 = erow[2 * lane], v1 = erow[2 * lane + 1];
    float m = fmaxf(fmaxf(fmaxf(v0.x, v0.y), fmaxf(v0.z, v0.w)),
                    fmaxf(fmaxf(v1.x, v1.y), fmaxf(v1.z, v1.w)));
    #pragma unroll
    for (int off = 32; off > 0; off >>= 1) m = fmaxf(m, __shfl_xor(m, off, 64));
    float p[8];
    p[0] = __expf(v0.x - m); p[1] = __expf(v0.y - m);
    p[2] = __expf(v0.z - m); p[3] = __expf(v0.w - m);
    p[4] = __expf(v1.x - m); p[5] = __expf(v1.y - m);
    p[6] = __expf(v1.z - m); p[7] = __expf(v1.w - m);
    float s = ((p[0] + p[1]) + (p[2] + p[3])) + ((p[4] + p[5]) + (p[6] + p[7]));
    #pragma unroll
    for (int off = 32; off > 0; off >>= 1) s += __shfl_xor(s, off, 64);
    const float inv = 1.0f / s;
    ushort4 h0, h1, l0, l1;
    split_bf16(p[0] * inv, h0.x, l0.x); split_bf16(p[1] * inv, h0.y, l0.y);
    split_bf16(p[2] * inv, h0.z, l0.z); split_bf16(p[3] * inv, h0.w, l0.w);
    split_bf16(p[4] * inv, h1.x, l1.x); split_bf16(p[5] * inv, h1.y, l1.y);
    split_bf16(p[6] * inv, h1.z, l1.z); split_bf16(p[7] * inv, h1.w, l1.w);
    ushort4* oh = (ushort4*)(aH + (size_t)row * LSEQ);
    ushort4* ol = (ushort4*)(aL + (size_t)row * LSEQ);
    oh[2 * lane] = h0; oh[2 * lane + 1] = h1;
    ol[2 * lane] = l0; ol[2 * lane + 1] = l1;
}

// ---------------- k_vf: vf(n,d) = sum_l alpha(n,l) inp(l,d) per b; 3-pass split-bf16 MFMA.
// inp read fp32 reg-direct, split in-reg, transposed through swizzled LDS (u32 = lo<<16|hi).
// grid (8 d-groups, 32 b); wave owns d-tile wave*16; lane&15 = char row for A, d col for B.
__global__ __launch_bounds__(256) void k_vf(
    const float* __restrict__ inp,
    const ushort* __restrict__ aH, const ushort* __restrict__ aL,
    float* __restrict__ out_vf)
{
    __shared__ unsigned int tT[64 * 68];  // 17.4 KB, stride 68 + XOR granule swizzle
    const int dg = blockIdx.x, b = blockIdx.y;
    const int t = threadIdx.x;
    const int wave = t >> 6, lane = t & 63;
    const int d0 = dg * 64;
    const int lr = t >> 2;            // l-row 0..63 staged by this thread
    const int dcb = (t & 3) * 4;      // d-offset base

    const ushort* aHb = aH + (size_t)b * NCH * LSEQ + (size_t)(lane & 15) * LSEQ;
    const ushort* aLb = aL + (size_t)b * NCH * LSEQ + (size_t)(lane & 15) * LSEQ;
    const int dl = wave * 16 + (lane & 15);
    const int lloc = (lane >> 4) * 8;

    f32x4 acc[2] = {};

    for (int l0 = 0; l0 < LSEQ; l0 += 64) {
        #pragma unroll
        for (int q = 0; q < 4; ++q) {
            const int dc = dcb + 16 * q;
            float4 v = *(const float4*)&inp[((size_t)(b * LSEQ) + l0 + lr) * DIM + d0 + dc];
            float vv[4] = {v.x, v.y, v.z, v.w};
            #pragma unroll
            for (int i = 0; i < 4; ++i) {
                ushort h, l; split_bf16(vv[i], h, l);
                const int d = dc + i;
                const int g = (lr >> 3) ^ (d & 7);
                tT[d * 68 + g * 8 + (lr & 7)] = ((unsigned)l << 16) | (unsigned)h;
            }
        }
        __syncthreads();
        #pragma unroll
        for (int sl = 0; sl < 2; ++sl) {
            const int ll = sl * 32 + lloc;
            const int gg = ((ll >> 3) ^ (dl & 7)) * 8;
            const uint4* srcp = (const uint4*)&tT[dl * 68 + gg];
            uint4 w0 = srcp[0], w1 = srcp[1];
            union { unsigned u[4]; bf16x8 v; } H, L;
            H.u[0] = (w0.x & 0xFFFFu) | (w0.y << 16);
            H.u[1] = (w0.z & 0xFFFFu) | (w0.w << 16);
            H.u[2] = (w1.x & 0xFFFFu) | (w1.y << 16);
            H.u[3] = (w1.z & 0xFFFFu) | (w1.w << 16);
            L.u[0] = (w0.x >> 16) | (w0.y & 0xFFFF0000u);
            L.u[1] = (w0.z >> 16) | (w0.w & 0xFFFF0000u);
            L.u[2] = (w1.x >> 16) | (w1.y & 0xFFFF0000u);
            L.u[3] = (w1.z >> 16) | (w1.w & 0xFFFF0000u);

            const bf16x8 ah0 = *(const bf16x8*)&aHb[l0 + ll];
            const bf16x8 ah1 = *(const bf16x8*)&aHb[16 * LSEQ + l0 + ll];
            const bf16x8 al0 = *(const bf16x8*)&aLb[l0 + ll];
            const bf16x8 al1 = *(const bf16x8*)&aLb[16 * LSEQ + l0 + ll];

            acc[0] = __builtin_amdgcn_mfma_f32_16x16x32_bf16(ah0, H.v, acc[0], 0, 0, 0);
            acc[0] = __builtin_amdgcn_mfma_f32_16x16x32_bf16(ah0, L.v, acc[0], 0, 0, 0);
            acc[0] = __builtin_amdgcn_mfma_f32_16x16x32_bf16(al0, H.v, acc[0], 0, 0, 0);
            acc[1] = __builtin_amdgcn_mfma_f32_16x16x32_bf16(ah1, H.v, acc[1], 0, 0, 0);
            acc[1] = __builtin_amdgcn_mfma_f32_16x16x32_bf16(ah1, L.v, acc[1], 0, 0, 0);
            acc[1] = __builtin_amdgcn_mfma_f32_16x16x32_bf16(al1, H.v, acc[1], 0, 0, 0);
        }
        __syncthreads();
    }

    const int dcol = d0 + dl;
    #pragma unroll
    for (int m = 0; m < 2; ++m) {
        const int ch = m * 16 + (lane >> 4) * 4;
        #pragma unroll
        for (int r = 0; r < 4; ++r)
            out_vf[(size_t)(b * NCH + ch + r) * DIM + dcol] = acc[m][r];
    }
}

// ---------------- k_lg: logits = vf @ Wc + b. Block per 4 rows (Wc shared 4x).
__global__ __launch_bounds__(256) void k_lg(
    const float* __restrict__ vf, const float* __restrict__ Wc_w,
    const float* __restrict__ Wc_b, float* __restrict__ out_logits)
{
    __shared__ float vfS[4][DIM];
    __shared__ float lgS[2][4][NDICT];
    const int r0 = blockIdx.x * 4;
    const int t = threadIdx.x;
    const int wave = t >> 6, lane = t & 63;

    const float2* src = (const float2*)(vf + (size_t)(r0 + wave) * DIM);
    #pragma unroll
    for (int q = 0; q < 4; ++q)
        ((float2*)&vfS[wave][0])[lane + 64 * q] = src[lane + 64 * q];
    __syncthreads();

    const int j = t & 127, half = t >> 7;
    if (j < NDICT) {
        const float* wc = Wc_w + (size_t)half * 256 * NDICT + j;
        const float* v0 = &vfS[0][half * 256];
        const float* v1 = &vfS[1][half * 256];
        const float* v2 = &vfS[2][half * 256];
        const float* v3 = &vfS[3][half * 256];
        float a0 = 0.f, a1 = 0.f, a2 = 0.f, a3 = 0.f;
        #pragma unroll 4
        for (int d = 0; d < 256; ++d) {
            float w = wc[(size_t)d * NDICT];
            a0 = fmaf(v0[d], w, a0); a1 = fmaf(v1[d], w, a1);
            a2 = fmaf(v2[d], w, a2); a3 = fmaf(v3[d], w, a3);
        }
        lgS[half][0][j] = a0; lgS[half][1][j] = a1;
        lgS[half][2][j] = a2; lgS[half][3][j] = a3;
    }
    __syncthreads();
    for (int idx = t; idx < 4 * NDICT; idx += 256) {
        const int r = idx / NDICT, jj = idx - r * NDICT;
        out_logits[(size_t)(r0 + r) * NDICT + jj] = Wc_b[jj] + lgS[0][r][jj] + lgS[1][r][jj];
    }
}

extern "C" void kernel_launch(void* const* d_in, const int* in_sizes, int n_in,
                              void* d_out, int out_size, void* d_ws, size_t ws_size,
                              hipStream_t stream)
{
    const float* inp  = (const float*)d_in[0];
    const float* emb  = (const float*)d_in[1];
    const float* Wo_w = (const float*)d_in[2];
    const float* Wo_b = (const float*)d_in[3];
    const float* Wv_w = (const float*)d_in[4];
    const float* Wv_b = (const float*)d_in[5];
    const float* We_w = (const float*)d_in[6];
    // d_in[7] = We_b: unused (softmax shift-invariant; e not an output)
    const float* Wc_w = (const float*)d_in[8];
    const float* Wc_b = (const float*)d_in[9];

    char* p = (char*)d_ws;
    float*  w_o  = (float*)p;   p += (64 << 10);
    float*  ev   = (float*)p;   p += (size_t)BS * NCH * LSEQ * 4;      // 2 MB
    ushort* BhiT = (ushort*)p;  p += (size_t)DIM * DIM * 2;            // 512 KB
    ushort* BloT = (ushort*)p;  p += (size_t)DIM * DIM * 2;
    ushort* aH   = (ushort*)p;  p += (size_t)BS * NCH * LSEQ * 2;      // 1 MB
    ushort* aL   = (ushort*)p;  p += (size_t)BS * NCH * LSEQ * 2;
    float*  w_v  = (float*)p;                                           // 33.5 MB

    float* out_vf = (float*)d_out;
    float* out_lg = out_vf + BS * NCH * DIM;

    k_misc<<<dim3(96), dim3(256), 0, stream>>>(Wv_w, BhiT, BloT, emb, Wo_w, Wo_b, w_o);
    k_gemm<<<dim3(512), dim3(256), 0, stream>>>(inp, BhiT, BloT, Wv_b, w_v);
    k_e<<<dim3(LSEQ / 16, BS, NCH / CHB), dim3(256), 0, stream>>>(w_v, w_o, We_w, ev);
    k_soft<<<dim3(256), dim3(256), 0, stream>>>(ev, aH, aL);
    k_vf<<<dim3(8, BS), dim3(256), 0, stream>>>(inp, aH, aL, out_vf);
    k_lg<<<dim3(256), dim3(256), 0, stream>>>(out_vf, Wc_w, Wc_b, out_lg);
}